// Round 1
// baseline (1350.269 us; speedup 1.0000x reference)
//
#include <hip/hip_runtime.h>

#define NND 50000
#define NE  1600000
#define TT  8
#define NBS ((NND + 255) / 256)   // 196 blocks over nodes

// ---------------- preprocessing ----------------

__global__ void k_init(int* __restrict__ deg, float* __restrict__ ppool) {
  int i = blockIdx.x * 256 + threadIdx.x;
  if (i < NND) deg[i] = 1;              // self-loop
  if (i < TT * 64) ppool[i] = 0.f;
}

__global__ void k_deg(const int* __restrict__ ei, int* __restrict__ deg) {
  int e = blockIdx.x * 256 + threadIdx.x;
  if (e < NE) atomicAdd(&deg[ei[NE + e]], 1);
}

__global__ void k_dinv(const int* __restrict__ deg, float* __restrict__ dinv) {
  int n = blockIdx.x * 256 + threadIdx.x;
  if (n < NND) dinv[n] = rsqrtf((float)deg[n]);
}

__global__ void k_scan1(const int* __restrict__ deg, int* __restrict__ bsum) {
  __shared__ int sh[256];
  int n = blockIdx.x * 256 + threadIdx.x;
  sh[threadIdx.x] = (n < NND) ? deg[n] : 0;
  __syncthreads();
  for (int o = 128; o > 0; o >>= 1) {
    if (threadIdx.x < o) sh[threadIdx.x] += sh[threadIdx.x + o];
    __syncthreads();
  }
  if (threadIdx.x == 0) bsum[blockIdx.x] = sh[0];
}

__global__ void k_scan2(const int* __restrict__ bsum, int* __restrict__ boff) {
  __shared__ int sh[256];
  int tid = threadIdx.x;
  int v = (tid < NBS) ? bsum[tid] : 0;
  sh[tid] = v;
  __syncthreads();
  for (int o = 1; o < 256; o <<= 1) {
    int t = (tid >= o) ? sh[tid - o] : 0;
    __syncthreads();
    sh[tid] += t;
    __syncthreads();
  }
  boff[tid] = sh[tid] - v;  // exclusive
}

__global__ void k_scan3(const int* __restrict__ deg, const int* __restrict__ boff,
                        int* __restrict__ offs, int* __restrict__ cursor,
                        int* __restrict__ csr) {
  __shared__ int sh[256];
  int tid = threadIdx.x;
  int n = blockIdx.x * 256 + tid;
  int v = (n < NND) ? deg[n] : 0;
  sh[tid] = v;
  __syncthreads();
  for (int o = 1; o < 256; o <<= 1) {
    int t2 = (tid >= o) ? sh[tid - o] : 0;
    __syncthreads();
    sh[tid] += t2;
    __syncthreads();
  }
  if (n < NND) {
    int x = boff[blockIdx.x] + sh[tid] - v;  // exclusive global offset
    offs[n] = x;
    cursor[n] = x + 1;   // slot 0 of each node = self-loop
    csr[x] = n;
  }
}

__global__ void k_scatter(const int* __restrict__ ei, int* __restrict__ cursor,
                          int* __restrict__ csr) {
  int e = blockIdx.x * 256 + threadIdx.x;
  if (e < NE) {
    int d = ei[NE + e];
    int p = atomicAdd(&cursor[d], 1);
    csr[p] = ei[e];
  }
}

// x_seq [T][N][3] -> xs4 [N][T][4] (padded, pre-scaled by dinv[n])
__global__ void k_xs(const float* __restrict__ x, const float* __restrict__ dinv,
                     float* __restrict__ xs4) {
  int g = blockIdx.x * 256 + threadIdx.x;
  if (g >= NND * TT * 4) return;
  int n = g >> 5, r = g & 31, t = r >> 2, c = r & 3;
  float v = 0.f;
  if (c < 3) v = x[(t * NND + n) * 3 + c] * dinv[n];
  xs4[g] = v;
}

// ---------------- layer 1 ----------------

// y[n][t][0..2] = dinv[n] * sum_{s in nbr(n)} xs[s][t][0..2]   (8 threads per node)
__global__ void k_yagg(const int* __restrict__ offs, const int* __restrict__ deg,
                       const int* __restrict__ csr, const float4* __restrict__ xs4,
                       const float* __restrict__ dinv, float* __restrict__ y) {
  int g = blockIdx.x * 256 + threadIdx.x;
  int n = g >> 3, t = g & 7;
  if (n >= NND) return;
  int o0 = offs[n], d = deg[n];
  float a0 = 0.f, a1 = 0.f, a2 = 0.f;
  int i = 0;
  for (; i + 2 <= d; i += 2) {
    int s0 = csr[o0 + i], s1 = csr[o0 + i + 1];
    float4 v0 = xs4[s0 * 8 + t];
    float4 v1 = xs4[s1 * 8 + t];
    a0 += v0.x + v1.x; a1 += v0.y + v1.y; a2 += v0.z + v1.z;
  }
  if (i < d) {
    float4 v = xs4[csr[o0 + i] * 8 + t];
    a0 += v.x; a1 += v.y; a2 += v.z;
  }
  float dn = dinv[n];
  int b = (n * TT + t) * 3;
  y[b] = a0 * dn; y[b + 1] = a1 * dn; y[b + 2] = a2 * dn;
}

// h1s[n][c] = dinv[n] * relu(y[n][t]·W1[:,c] + b1[c])
__global__ void k_h1(const float* __restrict__ y, const float* __restrict__ W1,
                     const float* __restrict__ b1, const float* __restrict__ dinv,
                     float* __restrict__ h1s, int t) {
  int g = blockIdx.x * 256 + threadIdx.x;
  int n = g >> 6, c = g & 63;
  if (n >= NND) return;
  int b = (n * TT + t) * 3;
  float y0 = y[b], y1 = y[b + 1], y2 = y[b + 2];
  float v = fmaf(y2, W1[128 + c], fmaf(y1, W1[64 + c], fmaf(y0, W1[c], b1[c])));
  h1s[g] = fmaxf(v, 0.f) * dinv[n];
}

// ---------------- layer 2 ----------------

// agg2[n][c] = dinv[n] * sum_{s in nbr(n)} h1s[s][c]   (wave per node, lane=c)
__global__ void k_agg2(const int* __restrict__ offs, const int* __restrict__ deg,
                       const int* __restrict__ csr, const float* __restrict__ h1s,
                       const float* __restrict__ dinv, float* __restrict__ agg2) {
  int g = blockIdx.x * 256 + threadIdx.x;
  int n = g >> 6, c = g & 63;
  if (n >= NND) return;
  int o0 = offs[n], d = deg[n];
  float acc = 0.f;
  int i = 0;
  for (; i + 4 <= d; i += 4) {
    int s0 = csr[o0 + i], s1 = csr[o0 + i + 1];
    int s2 = csr[o0 + i + 2], s3 = csr[o0 + i + 3];
    float v0 = h1s[(s0 << 6) + c];
    float v1 = h1s[(s1 << 6) + c];
    float v2 = h1s[(s2 << 6) + c];
    float v3 = h1s[(s3 << 6) + c];
    acc += v0; acc += v1; acc += v2; acc += v3;
  }
  for (; i < d; ++i) acc += h1s[(csr[o0 + i] << 6) + c];
  agg2[g] = acc * dinv[n];
}

// C = agg2[N,64] @ W2[64,64]; pool += sum_rows relu(C + b2). Tile 128 rows/block.
__launch_bounds__(256)
__global__ void k_gemm_pool(const float* __restrict__ agg2, const float* __restrict__ W2,
                            const float* __restrict__ b2, float* __restrict__ ppool, int t) {
  __shared__ float As[128 * 64];   // 32 KB, chunk-swizzled
  __shared__ float Ws[64 * 64];    // 16 KB, W2^T, chunk-swizzled
  __shared__ float pool[64];
  int tid = threadIdx.x;
  int rows0 = blockIdx.x * 128;
  if (tid < 64) pool[tid] = 0.f;
  // Ws[j][swz(k)] = W2[k][j]
  for (int i = 0; i < 16; ++i) {
    int idx = i * 256 + tid;
    int k = idx >> 6, j = idx & 63;
    Ws[j * 64 + (((k >> 2) ^ ((j >> 3) & 7)) << 2) + (k & 3)] = W2[idx];
  }
  // As[row][swz(k)] = agg2[rows0+row][k]
  const float4* a4 = (const float4*)agg2;
  for (int i = 0; i < 8; ++i) {
    int idx4 = i * 256 + tid;          // [0, 2048)
    int row = idx4 >> 4, k4 = idx4 & 15;
    int grow = rows0 + row;
    float4 v = make_float4(0.f, 0.f, 0.f, 0.f);
    if (grow < NND) v = a4[grow * 16 + k4];
    *(float4*)&As[row * 64 + ((k4 ^ ((row >> 3) & 7)) << 2)] = v;
  }
  __syncthreads();

  int rowg = tid >> 3, colg = tid & 7;
  int r0 = rowg * 4, c0 = colg * 8;
  float acc[4][8];
  for (int a = 0; a < 4; ++a)
    for (int b = 0; b < 8; ++b) acc[a][b] = 0.f;
  for (int k4 = 0; k4 < 16; ++k4) {
    float4 w[8];
    for (int cc = 0; cc < 8; ++cc)
      w[cc] = *(const float4*)&Ws[(c0 + cc) * 64 + ((k4 ^ colg) << 2)];
    for (int rr = 0; rr < 4; ++rr) {
      int r = r0 + rr;
      float4 av = *(const float4*)&As[r * 64 + ((k4 ^ ((r >> 3) & 7)) << 2)];
      for (int cc = 0; cc < 8; ++cc) {
        acc[rr][cc] += av.x * w[cc].x;
        acc[rr][cc] += av.y * w[cc].y;
        acc[rr][cc] += av.z * w[cc].z;
        acc[rr][cc] += av.w * w[cc].w;
      }
    }
  }

  float b2c[8];
  for (int cc = 0; cc < 8; ++cc) b2c[cc] = b2[c0 + cc];
  float csum[8];
  for (int cc = 0; cc < 8; ++cc) csum[cc] = 0.f;
  for (int rr = 0; rr < 4; ++rr) {
    if (rows0 + r0 + rr < NND) {
      for (int cc = 0; cc < 8; ++cc)
        csum[cc] += fmaxf(acc[rr][cc] + b2c[cc], 0.f);
    }
  }
  for (int cc = 0; cc < 8; ++cc) atomicAdd(&pool[c0 + cc], csum[cc]);
  __syncthreads();
  if (tid < 64) atomicAdd(&ppool[t * 64 + tid], pool[tid]);
}

// ---------------- GRU + fc ----------------

__global__ void k_twih(const float* __restrict__ w, float* __restrict__ wt) {
  int g = blockIdx.x * 256 + threadIdx.x;
  if (g < 384 * 64) { int r = g >> 6, k = g & 63; wt[k * 384 + r] = w[g]; }
}
__global__ void k_twhh(const float* __restrict__ w, float* __restrict__ wt) {
  int g = blockIdx.x * 256 + threadIdx.x;
  if (g < 384 * 128) { int r = g >> 7, k = g & 127; wt[k * 384 + r] = w[g]; }
}

__global__ void k_gru(const float* __restrict__ ppool, const float* __restrict__ wihT,
                      const float* __restrict__ whhT, const float* __restrict__ b_ih,
                      const float* __restrict__ b_hh, const float* __restrict__ fc_w,
                      const float* __restrict__ fc_b, float* __restrict__ out) {
  __shared__ float x[64], h[128], red[128];
  int j = threadIdx.x;  // 128 threads
  h[j] = 0.f;
  __syncthreads();
  for (int t = 0; t < TT; ++t) {
    if (j < 64) x[j] = ppool[t * 64 + j] * (1.0f / (float)NND);
    __syncthreads();
    float gr = b_ih[j], gz = b_ih[128 + j], gn = b_ih[256 + j];
    for (int k = 0; k < 64; ++k) {
      float xv = x[k];
      const float* wb = wihT + k * 384;
      gr = fmaf(wb[j], xv, gr);
      gz = fmaf(wb[128 + j], xv, gz);
      gn = fmaf(wb[256 + j], xv, gn);
    }
    float hr = b_hh[j], hz = b_hh[128 + j], hn = b_hh[256 + j];
    for (int k = 0; k < 128; ++k) {
      float hv = h[k];
      const float* wb = whhT + k * 384;
      hr = fmaf(wb[j], hv, hr);
      hz = fmaf(wb[128 + j], hv, hz);
      hn = fmaf(wb[256 + j], hv, hn);
    }
    float r = 1.f / (1.f + expf(-(gr + hr)));
    float z = 1.f / (1.f + expf(-(gz + hz)));
    float nn = tanhf(gn + r * hn);
    float hnew = (1.f - z) * nn + z * h[j];
    __syncthreads();
    h[j] = hnew;
    __syncthreads();
  }
  red[j] = h[j] * fc_w[j];
  __syncthreads();
  for (int o = 64; o > 0; o >>= 1) {
    if (j < o) red[j] += red[j + o];
    __syncthreads();
  }
  if (j == 0) out[0] = red[0] + fc_b[0];
}

// ---------------- launch ----------------

extern "C" void kernel_launch(void* const* d_in, const int* in_sizes, int n_in,
                              void* d_out, int out_size, void* d_ws, size_t ws_size,
                              hipStream_t stream) {
  const float* x_seq = (const float*)d_in[0];
  const int*   ei    = (const int*)d_in[1];
  const float* W1    = (const float*)d_in[2];
  const float* b1    = (const float*)d_in[3];
  const float* W2    = (const float*)d_in[4];
  const float* b2    = (const float*)d_in[5];
  const float* w_ih  = (const float*)d_in[6];
  const float* w_hh  = (const float*)d_in[7];
  const float* b_ih  = (const float*)d_in[8];
  const float* b_hh  = (const float*)d_in[9];
  const float* fc_w  = (const float*)d_in[10];
  const float* fc_b  = (const float*)d_in[11];
  float* out = (float*)d_out;

  char* p = (char*)d_ws;
  size_t off = 0;
  auto carve = [&](size_t bytes) -> char* {
    char* q = p + off;
    off += (bytes + 255) & ~(size_t)255;
    return q;
  };
  int*   deg    = (int*)carve((size_t)NND * 4);
  float* dinv   = (float*)carve((size_t)NND * 4);
  int*   offs   = (int*)carve((size_t)NND * 4);
  int*   cursor = (int*)carve((size_t)NND * 4);
  int*   bsum   = (int*)carve(256 * 4);
  int*   boff   = (int*)carve(256 * 4);
  int*   csr    = (int*)carve((size_t)(NE + NND) * 4);
  float* xs4    = (float*)carve((size_t)NND * TT * 4 * 4);
  float* y      = (float*)carve((size_t)NND * TT * 3 * 4);
  float* h1s    = (float*)carve((size_t)NND * 64 * 4);
  float* agg2   = (float*)carve((size_t)NND * 64 * 4);
  float* ppool  = (float*)carve((size_t)TT * 64 * 4);
  float* wihT   = (float*)carve((size_t)384 * 64 * 4);
  float* whhT   = (float*)carve((size_t)384 * 128 * 4);

  k_init<<<NBS, 256, 0, stream>>>(deg, ppool);
  k_deg<<<(NE + 255) / 256, 256, 0, stream>>>(ei, deg);
  k_dinv<<<NBS, 256, 0, stream>>>(deg, dinv);
  k_scan1<<<NBS, 256, 0, stream>>>(deg, bsum);
  k_scan2<<<1, 256, 0, stream>>>(bsum, boff);
  k_scan3<<<NBS, 256, 0, stream>>>(deg, boff, offs, cursor, csr);
  k_scatter<<<(NE + 255) / 256, 256, 0, stream>>>(ei, cursor, csr);
  k_xs<<<(NND * TT * 4 + 255) / 256, 256, 0, stream>>>(x_seq, dinv, xs4);
  k_yagg<<<(NND * TT + 255) / 256, 256, 0, stream>>>(offs, deg, csr,
                                                     (const float4*)xs4, dinv, y);
  k_twih<<<(384 * 64 + 255) / 256, 256, 0, stream>>>(w_ih, wihT);
  k_twhh<<<(384 * 128 + 255) / 256, 256, 0, stream>>>(w_hh, whhT);

  for (int t = 0; t < TT; ++t) {
    k_h1<<<(NND * 64 + 255) / 256, 256, 0, stream>>>(y, W1, b1, dinv, h1s, t);
    k_agg2<<<(NND * 64 + 255) / 256, 256, 0, stream>>>(offs, deg, csr, h1s, dinv, agg2);
    k_gemm_pool<<<(NND + 127) / 128, 256, 0, stream>>>(agg2, W2, b2, ppool, t);
  }

  k_gru<<<1, 128, 0, stream>>>(ppool, wihT, whhT, b_ih, b_hh, fc_w, fc_b, out);
}

// Round 3
// 1069.762 us; speedup vs baseline: 1.2622x; 1.2622x over previous
//
#include <hip/hip_runtime.h>

#define NND 50000
#define NE  1600000
#define TT  8
#define NBS ((NND + 255) / 256)   // 196 blocks over nodes

// ---------------- preprocessing ----------------

__global__ void k_init(int* __restrict__ deg, float* __restrict__ ppool) {
  int i = blockIdx.x * 256 + threadIdx.x;
  if (i < NND) deg[i] = 1;              // self-loop
  if (i < TT * 64) ppool[i] = 0.f;
}

__global__ void k_deg(const int* __restrict__ ei, int* __restrict__ deg) {
  int e = blockIdx.x * 256 + threadIdx.x;
  if (e < NE) atomicAdd(&deg[ei[NE + e]], 1);
}

__global__ void k_dinv(const int* __restrict__ deg, float* __restrict__ dinv) {
  int n = blockIdx.x * 256 + threadIdx.x;
  if (n < NND) dinv[n] = rsqrtf((float)deg[n]);
}

__global__ void k_scan1(const int* __restrict__ deg, int* __restrict__ bsum) {
  __shared__ int sh[256];
  int n = blockIdx.x * 256 + threadIdx.x;
  sh[threadIdx.x] = (n < NND) ? deg[n] : 0;
  __syncthreads();
  for (int o = 128; o > 0; o >>= 1) {
    if (threadIdx.x < o) sh[threadIdx.x] += sh[threadIdx.x + o];
    __syncthreads();
  }
  if (threadIdx.x == 0) bsum[blockIdx.x] = sh[0];
}

__global__ void k_scan2(const int* __restrict__ bsum, int* __restrict__ boff) {
  __shared__ int sh[256];
  int tid = threadIdx.x;
  int v = (tid < NBS) ? bsum[tid] : 0;
  sh[tid] = v;
  __syncthreads();
  for (int o = 1; o < 256; o <<= 1) {
    int t = (tid >= o) ? sh[tid - o] : 0;
    __syncthreads();
    sh[tid] += t;
    __syncthreads();
  }
  boff[tid] = sh[tid] - v;  // exclusive
}

__global__ void k_scan3(const int* __restrict__ deg, const int* __restrict__ boff,
                        int* __restrict__ offs, int* __restrict__ cursor,
                        int* __restrict__ csr) {
  __shared__ int sh[256];
  int tid = threadIdx.x;
  int n = blockIdx.x * 256 + tid;
  int v = (n < NND) ? deg[n] : 0;
  sh[tid] = v;
  __syncthreads();
  for (int o = 1; o < 256; o <<= 1) {
    int t2 = (tid >= o) ? sh[tid - o] : 0;
    __syncthreads();
    sh[tid] += t2;
    __syncthreads();
  }
  if (n < NND) {
    int x = boff[blockIdx.x] + sh[tid] - v;  // exclusive global offset
    offs[n] = x;
    cursor[n] = x + 1;   // slot 0 of each node = self-loop
    csr[x] = n;
  }
}

__global__ void k_scatter(const int* __restrict__ ei, int* __restrict__ cursor,
                          int* __restrict__ csr) {
  int e = blockIdx.x * 256 + threadIdx.x;
  if (e < NE) {
    int d = ei[NE + e];
    int p = atomicAdd(&cursor[d], 1);
    csr[p] = ei[e];
  }
}

// x_seq [T][N][3] -> xs4 [N][T][4] (padded, pre-scaled by dinv[n])
__global__ void k_xs(const float* __restrict__ x, const float* __restrict__ dinv,
                     float* __restrict__ xs4) {
  int g = blockIdx.x * 256 + threadIdx.x;
  if (g >= NND * TT * 4) return;
  int n = g >> 5, r = g & 31, t = r >> 2, c = r & 3;
  float v = 0.f;
  if (c < 3) v = x[(t * NND + n) * 3 + c] * dinv[n];
  xs4[g] = v;
}

// ---------------- layer 1 ----------------

// y[n][t][0..2] = dinv[n] * sum_{s in nbr(n)} xs[s][t][0..2]   (8 threads per node)
__global__ void k_yagg(const int* __restrict__ offs, const int* __restrict__ deg,
                       const int* __restrict__ csr, const float4* __restrict__ xs4,
                       const float* __restrict__ dinv, float* __restrict__ y) {
  int g = blockIdx.x * 256 + threadIdx.x;
  int n = g >> 3, t = g & 7;
  if (n >= NND) return;
  int o0 = offs[n], d = deg[n];
  float a0 = 0.f, a1 = 0.f, a2 = 0.f;
  int i = 0;
  for (; i + 2 <= d; i += 2) {
    int s0 = csr[o0 + i], s1 = csr[o0 + i + 1];
    float4 v0 = xs4[s0 * 8 + t];
    float4 v1 = xs4[s1 * 8 + t];
    a0 += v0.x + v1.x; a1 += v0.y + v1.y; a2 += v0.z + v1.z;
  }
  if (i < d) {
    float4 v = xs4[csr[o0 + i] * 8 + t];
    a0 += v.x; a1 += v.y; a2 += v.z;
  }
  float dn = dinv[n];
  int b = (n * TT + t) * 3;
  y[b] = a0 * dn; y[b + 1] = a1 * dn; y[b + 2] = a2 * dn;
}

// h1s[n][c] = dinv[n] * relu(y[n][t]·W1[:,c] + b1[c])
__global__ void k_h1(const float* __restrict__ y, const float* __restrict__ W1,
                     const float* __restrict__ b1, const float* __restrict__ dinv,
                     float* __restrict__ h1s, int t) {
  int g = blockIdx.x * 256 + threadIdx.x;
  int n = g >> 6, c = g & 63;
  if (n >= NND) return;
  int b = (n * TT + t) * 3;
  float y0 = y[b], y1 = y[b + 1], y2 = y[b + 2];
  float v = fmaf(y2, W1[128 + c], fmaf(y1, W1[64 + c], fmaf(y0, W1[c], b1[c])));
  h1s[g] = fmaxf(v, 0.f) * dinv[n];
}

// ---------------- layer 2 ----------------

// agg2[n][c] = dinv[n] * sum_{s in nbr(n)} h1s[s][c]   (wave per node, lane=c)
__global__ void k_agg2(const int* __restrict__ offs, const int* __restrict__ deg,
                       const int* __restrict__ csr, const float* __restrict__ h1s,
                       const float* __restrict__ dinv, float* __restrict__ agg2) {
  int g = blockIdx.x * 256 + threadIdx.x;
  int n = g >> 6, c = g & 63;
  if (n >= NND) return;
  int o0 = offs[n], d = deg[n];
  float acc = 0.f;
  int i = 0;
  for (; i + 4 <= d; i += 4) {
    int s0 = csr[o0 + i], s1 = csr[o0 + i + 1];
    int s2 = csr[o0 + i + 2], s3 = csr[o0 + i + 3];
    float v0 = h1s[(s0 << 6) + c];
    float v1 = h1s[(s1 << 6) + c];
    float v2 = h1s[(s2 << 6) + c];
    float v3 = h1s[(s3 << 6) + c];
    acc += v0; acc += v1; acc += v2; acc += v3;
  }
  for (; i < d; ++i) acc += h1s[(csr[o0 + i] << 6) + c];
  agg2[g] = acc * dinv[n];
}

// C = agg2[N,64] @ W2[64,64]; pool += sum_rows relu(C + b2). Tile 128 rows/block.
__launch_bounds__(256)
__global__ void k_gemm_pool(const float* __restrict__ agg2, const float* __restrict__ W2,
                            const float* __restrict__ b2, float* __restrict__ ppool, int t) {
  __shared__ float As[128 * 64];   // 32 KB, chunk-swizzled
  __shared__ float Ws[64 * 64];    // 16 KB, W2^T, chunk-swizzled
  __shared__ float pool[64];
  int tid = threadIdx.x;
  int rows0 = blockIdx.x * 128;
  if (tid < 64) pool[tid] = 0.f;
  // Ws[j][swz(k)] = W2[k][j]
  for (int i = 0; i < 16; ++i) {
    int idx = i * 256 + tid;
    int k = idx >> 6, j = idx & 63;
    Ws[j * 64 + (((k >> 2) ^ ((j >> 3) & 7)) << 2) + (k & 3)] = W2[idx];
  }
  // As[row][swz(k)] = agg2[rows0+row][k]
  const float4* a4 = (const float4*)agg2;
  for (int i = 0; i < 8; ++i) {
    int idx4 = i * 256 + tid;          // [0, 2048)
    int row = idx4 >> 4, k4 = idx4 & 15;
    int grow = rows0 + row;
    float4 v = make_float4(0.f, 0.f, 0.f, 0.f);
    if (grow < NND) v = a4[grow * 16 + k4];
    *(float4*)&As[row * 64 + ((k4 ^ ((row >> 3) & 7)) << 2)] = v;
  }
  __syncthreads();

  int rowg = tid >> 3, colg = tid & 7;
  int r0 = rowg * 4, c0 = colg * 8;
  float acc[4][8];
  for (int a = 0; a < 4; ++a)
    for (int b = 0; b < 8; ++b) acc[a][b] = 0.f;
  for (int k4 = 0; k4 < 16; ++k4) {
    float4 w[8];
    for (int cc = 0; cc < 8; ++cc)
      w[cc] = *(const float4*)&Ws[(c0 + cc) * 64 + ((k4 ^ colg) << 2)];
    for (int rr = 0; rr < 4; ++rr) {
      int r = r0 + rr;
      float4 av = *(const float4*)&As[r * 64 + ((k4 ^ ((r >> 3) & 7)) << 2)];
      for (int cc = 0; cc < 8; ++cc) {
        acc[rr][cc] += av.x * w[cc].x;
        acc[rr][cc] += av.y * w[cc].y;
        acc[rr][cc] += av.z * w[cc].z;
        acc[rr][cc] += av.w * w[cc].w;
      }
    }
  }

  float b2c[8];
  for (int cc = 0; cc < 8; ++cc) b2c[cc] = b2[c0 + cc];
  float csum[8];
  for (int cc = 0; cc < 8; ++cc) csum[cc] = 0.f;
  for (int rr = 0; rr < 4; ++rr) {
    if (rows0 + r0 + rr < NND) {
      for (int cc = 0; cc < 8; ++cc)
        csum[cc] += fmaxf(acc[rr][cc] + b2c[cc], 0.f);
    }
  }
  for (int cc = 0; cc < 8; ++cc) atomicAdd(&pool[c0 + cc], csum[cc]);
  __syncthreads();
  if (tid < 64) atomicAdd(&ppool[t * 64 + tid], pool[tid]);
}

// ---------------- GRU + fc ----------------

__global__ void k_twih(const float* __restrict__ w, float* __restrict__ wt) {
  int g = blockIdx.x * 256 + threadIdx.x;
  if (g < 384 * 64) { int r = g >> 6, k = g & 63; wt[k * 384 + r] = w[g]; }
}
__global__ void k_twhh(const float* __restrict__ w, float* __restrict__ wt) {
  int g = blockIdx.x * 256 + threadIdx.x;
  if (g < 384 * 128) { int r = g >> 7, k = g & 127; wt[k * 384 + r] = w[g]; }
}

// One block, 384 threads: thread j owns gate-output j. Weight columns live in
// registers (64+128 floats/thread, fully unrolled preload) — read ONCE, not
// once per step (old version: 330 us of pure L2-latency at 2 waves).
__launch_bounds__(384, 2)
__global__ void k_gru(const float* __restrict__ ppool, const float* __restrict__ wihT,
                      const float* __restrict__ whhT, const float* __restrict__ b_ih,
                      const float* __restrict__ b_hh, const float* __restrict__ fc_w,
                      const float* __restrict__ fc_b, float* __restrict__ out) {
  __shared__ float x[64], h[128], gi_s[384], gh_s[384], red[128];
  int j = threadIdx.x;  // 0..383
  float wih[64];
#pragma unroll
  for (int k = 0; k < 64; ++k) wih[k] = wihT[k * 384 + j];
  float whh[128];
#pragma unroll
  for (int k = 0; k < 128; ++k) whh[k] = whhT[k * 384 + j];
  float bi = b_ih[j], bh = b_hh[j];
  if (j < 128) h[j] = 0.f;
  const float invn = 1.0f / (float)NND;
  for (int t = 0; t < TT; ++t) {
    if (j < 64) x[j] = ppool[t * 64 + j] * invn;
    __syncthreads();
    float gi = bi, gh = bh;
#pragma unroll
    for (int k4 = 0; k4 < 16; ++k4) {
      float4 xv = *(const float4*)&x[k4 * 4];
      gi = fmaf(wih[k4 * 4 + 0], xv.x, gi);
      gi = fmaf(wih[k4 * 4 + 1], xv.y, gi);
      gi = fmaf(wih[k4 * 4 + 2], xv.z, gi);
      gi = fmaf(wih[k4 * 4 + 3], xv.w, gi);
    }
#pragma unroll
    for (int k4 = 0; k4 < 32; ++k4) {
      float4 hv = *(const float4*)&h[k4 * 4];
      gh = fmaf(whh[k4 * 4 + 0], hv.x, gh);
      gh = fmaf(whh[k4 * 4 + 1], hv.y, gh);
      gh = fmaf(whh[k4 * 4 + 2], hv.z, gh);
      gh = fmaf(whh[k4 * 4 + 3], hv.w, gh);
    }
    gi_s[j] = gi;
    gh_s[j] = gh;
    __syncthreads();
    if (j < 128) {
      float r = 1.f / (1.f + expf(-(gi_s[j] + gh_s[j])));
      float z = 1.f / (1.f + expf(-(gi_s[128 + j] + gh_s[128 + j])));
      float nn = tanhf(gi_s[256 + j] + r * gh_s[256 + j]);
      h[j] = (1.f - z) * nn + z * h[j];
    }
    __syncthreads();
  }
  if (j < 128) red[j] = h[j] * fc_w[j];
  __syncthreads();
  for (int o = 64; o > 0; o >>= 1) {
    if (j < o) red[j] += red[j + o];
    __syncthreads();
  }
  if (j == 0) out[0] = red[0] + fc_b[0];
}

// ---------------- launch ----------------

extern "C" void kernel_launch(void* const* d_in, const int* in_sizes, int n_in,
                              void* d_out, int out_size, void* d_ws, size_t ws_size,
                              hipStream_t stream) {
  const float* x_seq = (const float*)d_in[0];
  const int*   ei    = (const int*)d_in[1];
  const float* W1    = (const float*)d_in[2];
  const float* b1    = (const float*)d_in[3];
  const float* W2    = (const float*)d_in[4];
  const float* b2    = (const float*)d_in[5];
  const float* w_ih  = (const float*)d_in[6];
  const float* w_hh  = (const float*)d_in[7];
  const float* b_ih  = (const float*)d_in[8];
  const float* b_hh  = (const float*)d_in[9];
  const float* fc_w  = (const float*)d_in[10];
  const float* fc_b  = (const float*)d_in[11];
  float* out = (float*)d_out;

  char* p = (char*)d_ws;
  size_t off = 0;
  auto carve = [&](size_t bytes) -> char* {
    char* q = p + off;
    off += (bytes + 255) & ~(size_t)255;
    return q;
  };
  int*   deg    = (int*)carve((size_t)NND * 4);
  float* dinv   = (float*)carve((size_t)NND * 4);
  int*   offs   = (int*)carve((size_t)NND * 4);
  int*   cursor = (int*)carve((size_t)NND * 4);
  int*   bsum   = (int*)carve(256 * 4);
  int*   boff   = (int*)carve(256 * 4);
  int*   csr    = (int*)carve((size_t)(NE + NND) * 4);
  float* xs4    = (float*)carve((size_t)NND * TT * 4 * 4);
  float* y      = (float*)carve((size_t)NND * TT * 3 * 4);
  float* h1s    = (float*)carve((size_t)NND * 64 * 4);
  float* agg2   = (float*)carve((size_t)NND * 64 * 4);
  float* ppool  = (float*)carve((size_t)TT * 64 * 4);
  float* wihT   = (float*)carve((size_t)384 * 64 * 4);
  float* whhT   = (float*)carve((size_t)384 * 128 * 4);

  k_init<<<NBS, 256, 0, stream>>>(deg, ppool);
  k_deg<<<(NE + 255) / 256, 256, 0, stream>>>(ei, deg);
  k_dinv<<<NBS, 256, 0, stream>>>(deg, dinv);
  k_scan1<<<NBS, 256, 0, stream>>>(deg, bsum);
  k_scan2<<<1, 256, 0, stream>>>(bsum, boff);
  k_scan3<<<NBS, 256, 0, stream>>>(deg, boff, offs, cursor, csr);
  k_scatter<<<(NE + 255) / 256, 256, 0, stream>>>(ei, cursor, csr);
  k_xs<<<(NND * TT * 4 + 255) / 256, 256, 0, stream>>>(x_seq, dinv, xs4);
  k_yagg<<<(NND * TT + 255) / 256, 256, 0, stream>>>(offs, deg, csr,
                                                     (const float4*)xs4, dinv, y);
  k_twih<<<(384 * 64 + 255) / 256, 256, 0, stream>>>(w_ih, wihT);
  k_twhh<<<(384 * 128 + 255) / 256, 256, 0, stream>>>(w_hh, whhT);

  for (int t = 0; t < TT; ++t) {
    k_h1<<<(NND * 64 + 255) / 256, 256, 0, stream>>>(y, W1, b1, dinv, h1s, t);
    k_agg2<<<(NND * 64 + 255) / 256, 256, 0, stream>>>(offs, deg, csr, h1s, dinv, agg2);
    k_gemm_pool<<<(NND + 127) / 128, 256, 0, stream>>>(agg2, W2, b2, ppool, t);
  }

  k_gru<<<1, 384, 0, stream>>>(ppool, wihT, whhT, b_ih, b_hh, fc_w, fc_b, out);
}